// Round 4
// baseline (492.870 us; speedup 1.0000x reference)
//
#include <hip/hip_runtime.h>
#include <hip/hip_bf16.h>

#define B_    2
#define SQ_   2048
#define SK_   2048
#define HQ_   32
#define HKV_  8
#define D_    128
#define W_    512
#define QBLK  16
#define KVBLK 32
#define SROW  40   // shorts per bounce row: 32 kv + 8 pad; 80B rows keep b128 reads 16B-aligned, banks ~2-way

typedef short s16x8 __attribute__((ext_vector_type(8)));
typedef float f32x4 __attribute__((ext_vector_type(4)));

static __device__ __forceinline__ short bf16b(float x){
    __hip_bfloat16 h = __float2bfloat16(x);
    return *reinterpret_cast<short*>(&h);
}
static __device__ __forceinline__ float b2f(short u){
    return __uint_as_float(((unsigned int)(unsigned short)u) << 16);
}
static __device__ __forceinline__ float fexp2(float x){ return __builtin_amdgcn_exp2f(x); }
static __device__ __forceinline__ unsigned pk(float a, float b){
    return ((unsigned)(unsigned short)bf16b(a)) | (((unsigned)(unsigned short)bf16b(b)) << 16);
}

// ---- prep 1: cast K fp32 -> bf16 (same layout [b][sk][hkv][d]) ----
__global__ void cast_k_bf16(const float* __restrict__ k, short* __restrict__ kb){
    int idx = blockIdx.x * 256 + threadIdx.x;
    const float4* src = reinterpret_cast<const float4*>(k) + (size_t)idx * 2;
    float4 a = src[0], b = src[1];
    s16x8 o;
    o[0]=bf16b(a.x); o[1]=bf16b(a.y); o[2]=bf16b(a.z); o[3]=bf16b(a.w);
    o[4]=bf16b(b.x); o[5]=bf16b(b.y); o[6]=bf16b(b.z); o[7]=bf16b(b.w);
    reinterpret_cast<s16x8*>(kb)[idx] = o;
}

// ---- prep 2: V fp32 [b][sk][hkv][d] -> VT bf16 [b][hkv][d][sk] ----
__global__ void transpose_v(const float* __restrict__ v, short* __restrict__ vt){
    __shared__ short tT[32][66];
    int s0 = blockIdx.x * 64, d0 = blockIdx.y * 32, bh = blockIdx.z;
    int b = bh >> 3, hv = bh & 7;
    int tid = threadIdx.x;
    int s = tid >> 2, dq = (tid & 3) * 8;
    const float* src = v + ((size_t)(b * SK_ + s0 + s) * HKV_ + hv) * D_ + d0 + dq;
    float4 x = *reinterpret_cast<const float4*>(src);
    float4 y = *reinterpret_cast<const float4*>(src + 4);
    tT[dq + 0][s] = bf16b(x.x); tT[dq + 1][s] = bf16b(x.y);
    tT[dq + 2][s] = bf16b(x.z); tT[dq + 3][s] = bf16b(x.w);
    tT[dq + 4][s] = bf16b(y.x); tT[dq + 5][s] = bf16b(y.y);
    tT[dq + 6][s] = bf16b(y.z); tT[dq + 7][s] = bf16b(y.w);
    __syncthreads();
    int d = tid >> 3, so = (tid & 7) * 8;
    union { unsigned int u[4]; s16x8 v8; } o;
    #pragma unroll
    for (int k2 = 0; k2 < 4; ++k2)
        o.u[k2] = *reinterpret_cast<const unsigned int*>(&tT[d][so + k2 * 2]);
    short* dst = vt + ((size_t)(b * HKV_ + hv) * D_ + d0 + d) * SK_ + s0 + so;
    *reinterpret_cast<s16x8*>(dst) = o.v8;
}

// ---- main: recompute two-pass, zero persistent S.
// Swapped QK^T (mfma(K,Q) -> S^T): lane's q-row = c in every phase.
// Pass A: l_c only (2 shfl_xor total). Pass B: recompute u, bounce through
// 1.25KB LDS tile to PV A-frag layout, fused PV. 4 waves = 4 q-heads of one
// KV group share K/V through L1. No barriers (waves independent).
__global__ __launch_bounds__(256)
void attn_kernel(const float* __restrict__ q, const short* __restrict__ kb,
                 const short* __restrict__ vt, float* __restrict__ out){
    __shared__ short Pb[4 * 2 * QBLK * SROW];   // 10,240 B

    int bid = blockIdx.x;
    int swz = (bid & 7) * 256 + (bid >> 3);   // XCD-aware: each XCD works 2 (b,hkv) K/V ranges (2MB L2-resident)
    int qt  = swz & 127;
    int hkv = (swz >> 7) & 7;
    int b   = swz >> 10;
    int w    = threadIdx.x >> 6;
    int lane = threadIdx.x & 63;
    int h  = hkv * 4 + w;
    int qb = qt * QBLK;
    int g = lane >> 4, c = lane & 15;
    int qr = qb + c;                          // this lane's q row (swapped layout)

    short* PbS = Pb + w * (2 * QBLK * SROW);

    // Q fragments (B-operand): lane(g,c) holds Q[q=c][d=g*8+i] per 32-d block
    s16x8 qf[4];
    {
        const float* qrow = q + (((size_t)b * SQ_ + qb + c) * HQ_ + h) * D_;
        #pragma unroll
        for (int db = 0; db < 4; ++db){
            const float4* p = reinterpret_cast<const float4*>(qrow + db * 32 + g * 8);
            float4 x = p[0], y = p[1];
            s16x8 f;
            f[0]=bf16b(x.x); f[1]=bf16b(x.y); f[2]=bf16b(x.z); f[3]=bf16b(x.w);
            f[4]=bf16b(y.x); f[5]=bf16b(y.y); f[6]=bf16b(y.z); f[7]=bf16b(y.w);
            qf[db] = f;
        }
    }

    int lo = qb - W_; if (lo < 0) lo = 0;
    int t0 = lo & ~(KVBLK - 1);
    int t1 = (qb + QBLK - 1) & ~(KVBLK - 1);

    const float SCALE = 0.08838834764831845f;
    const float L2E   = 1.4426950408889634f;
    const float C1 = 2.0f * SCALE / 30.0f * L2E;   // e = exp2(acc*C1) = exp(2*logit/CAP)
    const float C2 = -60.0f * L2E;                 // u = exp2(C2*rcp(e+1) + C3) = exp(CAP*tanh)
    const float C3 =  30.0f * L2E;

    const short* kbase = kb + ((size_t)b * SK_ * HKV_ + hkv) * D_;

    // ---------------- pass A: row sums only ----------------
    float ls = 0.f;
    for (int t = t0; t <= t1; t += KVBLK){
        #pragma unroll
        for (int hh = 0; hh < 2; ++hh){
            int kvr = t + hh * 16 + c;
            const short* krow = kbase + (size_t)kvr * (HKV_ * D_);
            f32x4 acc = {0.f, 0.f, 0.f, 0.f};
            #pragma unroll
            for (int db = 0; db < 4; ++db){
                s16x8 kf = *reinterpret_cast<const s16x8*>(krow + db * 32 + g * 8);
                acc = __builtin_amdgcn_mfma_f32_16x16x32_bf16(kf, qf[db], acc, 0, 0, 0);
            }
            #pragma unroll
            for (int j = 0; j < 4; ++j){
                int kv = t + hh * 16 + 4 * g + j;
                float e = fexp2(acc[j] * C1);
                float r = __builtin_amdgcn_rcpf(e + 1.0f);
                float u = fexp2(fmaf(r, C2, C3));
                bool ok = (kv <= qr) && (kv >= qr - W_);
                ls += ok ? u : 0.f;
            }
        }
    }
    ls += __shfl_xor(ls, 16);
    ls += __shfl_xor(ls, 32);
    float rl = 1.02f / ls;

    // ---------------- pass B: recompute u, bounce, p', PV ----------------
    f32x4 o[8];
    #pragma unroll
    for (int dt = 0; dt < 8; ++dt) o[dt] = (f32x4){0.f, 0.f, 0.f, 0.f};

    const short* vbase = vt + (size_t)(b * HKV_ + hkv) * D_ * SK_;

    for (int t = t0; t <= t1; t += KVBLK){
        int tp = (t >> 5) & 1;
        unsigned* wb = reinterpret_cast<unsigned*>(PbS + tp * (QBLK * SROW));
        #pragma unroll
        for (int hh = 0; hh < 2; ++hh){
            int kvr = t + hh * 16 + c;
            const short* krow = kbase + (size_t)kvr * (HKV_ * D_);
            f32x4 acc = {0.f, 0.f, 0.f, 0.f};
            #pragma unroll
            for (int db = 0; db < 4; ++db){
                s16x8 kf = *reinterpret_cast<const s16x8*>(krow + db * 32 + g * 8);
                acc = __builtin_amdgcn_mfma_f32_16x16x32_bf16(kf, qf[db], acc, 0, 0, 0);
            }
            float u[4];
            #pragma unroll
            for (int j = 0; j < 4; ++j){
                int kv = t + hh * 16 + 4 * g + j;
                float e = fexp2(acc[j] * C1);
                float r = __builtin_amdgcn_rcpf(e + 1.0f);
                float uu = fexp2(fmaf(r, C2, C3));
                bool ok = (kv <= qr) && (kv >= qr - W_);
                u[j] = ok ? uu : 0.f;
            }
            // D-layout [kv=16hh+4g+2m(+1)][q=c] -> bounce row q=c, packed pairs
            wb[c * 20 + hh * 8 + g * 2 + 0] = pk(u[0], u[1]);
            wb[c * 20 + hh * 8 + g * 2 + 1] = pk(u[2], u[3]);
        }
        asm volatile("s_waitcnt lgkmcnt(0)" ::: "memory");
        // PV A-frag: lane(g,c) = P[q=c][kv = t+8g..+7]
        s16x8 pa = *reinterpret_cast<const s16x8*>(PbS + tp * (QBLK * SROW) + c * SROW + g * 8);
        s16x8 pf;
        #pragma unroll
        for (int i = 0; i < 8; ++i){
            float p = fmaf(b2f(pa[i]), rl, -0.01f);
            p = fminf(fmaxf(p, 0.f), 1.f);
            pf[i] = bf16b(p);
        }
        #pragma unroll
        for (int dt = 0; dt < 8; ++dt){
            s16x8 vf = *reinterpret_cast<const s16x8*>(vbase + (size_t)(dt * 16 + c) * SK_ + t + g * 8);
            o[dt] = __builtin_amdgcn_mfma_f32_16x16x32_bf16(pf, vf, o[dt], 0, 0, 0);
        }
    }

    // epilogue: o[dt][j] = O[q=4g+j][d=dt*16+c]
    float* obase = out + (((size_t)b * SQ_ + qb) * HQ_ + h) * D_;
    #pragma unroll
    for (int dt = 0; dt < 8; ++dt){
        #pragma unroll
        for (int j = 0; j < 4; ++j){
            obase[(size_t)(4 * g + j) * (HQ_ * D_) + dt * 16 + c] = o[dt][j];
        }
    }
}

extern "C" void kernel_launch(void* const* d_in, const int* in_sizes, int n_in,
                              void* d_out, int out_size, void* d_ws, size_t ws_size,
                              hipStream_t stream){
    const float* q = (const float*)d_in[0];
    const float* k = (const float*)d_in[1];
    const float* v = (const float*)d_in[2];
    float* out = (float*)d_out;

    short* kb  = (short*)d_ws;                 // 8 MiB
    short* vtp = (short*)d_ws + 4194304;       // 8 MiB

    cast_k_bf16<<<2048, 256, 0, stream>>>(k, kb);
    transpose_v<<<dim3(SK_ / 64, D_ / 32, B_ * HKV_), 256, 0, stream>>>(v, vtp);
    attn_kernel<<<B_ * HKV_ * (SQ_ / QBLK), 256, 0, stream>>>(q, kb, vtp, out);
}

// Round 5
// 226.529 us; speedup vs baseline: 2.1757x; 2.1757x over previous
//
#include <hip/hip_runtime.h>
#include <hip/hip_bf16.h>

#define B_    2
#define SQ_   2048
#define SK_   2048
#define HQ_   32
#define HKV_  8
#define D_    128
#define W_    512
#define KVT   64
#define MAXT  9

typedef short s16x8 __attribute__((ext_vector_type(8)));
typedef float f32x4 __attribute__((ext_vector_type(4)));

static __device__ __forceinline__ short bf16b(float x){
    __hip_bfloat16 h = __float2bfloat16(x);
    return *reinterpret_cast<short*>(&h);
}
static __device__ __forceinline__ float b2f(short u){
    return __uint_as_float(((unsigned)(unsigned short)u) << 16);
}
static __device__ __forceinline__ float fexp2(float x){ return __builtin_amdgcn_exp2f(x); }
static __device__ __forceinline__ unsigned pk2(float a, float b){
    return ((unsigned)(unsigned short)bf16b(a)) | (((unsigned)(unsigned short)bf16b(b)) << 16);
}

// Single fused kernel. Block = 512 threads = 8 waves = 4 q-heads x 2 q-subtiles(16 rows).
// Pass A: stage K tile (fp32->bf16, XOR-swizzled LDS), swapped QK^T (mfma(K,Q) -> S^T:
//   lane q-row = c for all phases), u = exp(CAP*tanh(.)) kept in REGISTERS (wv[9][8] bf16-packed).
// Pass B: stage V^T into the same LDS buffer, bounce wv through 2KB/wave LDS slice to
//   PV A-frag layout, p' = clamp(1.02*u/l - 0.01, 0, 1), fused PV.
// K read once, V read once, QK computed once. No prep kernels, no workspace.
__global__ __launch_bounds__(512)
void attn_kernel(const float* __restrict__ q, const float* __restrict__ k,
                 const float* __restrict__ v, float* __restrict__ out){
    __shared__ short KV[KVT * D_];        // 16 KB: K tile (pass A) / V^T tile (pass B)
    __shared__ short Pb[8 * 16 * KVT];    // 16 KB bounce: 2 KB per wave

    int bid = blockIdx.x;
    int swz = (bid & 7) * 128 + (bid >> 3);   // XCD-aware, bijective (1024 = 8*128)
    int qt  = swz & 63;
    int hkv = (swz >> 6) & 7;
    int b   = swz >> 9;
    int qb  = qt * 32;

    int tid  = threadIdx.x;
    int w    = tid >> 6;
    int lane = tid & 63;
    int hl = w >> 1, qs = w & 1;
    int h  = hkv * 4 + hl;
    int qlo = qb + qs * 16;
    int g = lane >> 4, c = lane & 15;
    int qr = qlo + c;                     // this lane's q row (swapped S^T layout)

    // tile range: cover [qb-512, qb+31], 64-aligned start, never past SK_
    int t0 = qb >= 512 ? ((qb - 512) & ~63) : 0;
    int nt = (qb + 32 - t0 + 63) >> 6;    // <= 9; t0 + nt*64 <= 2048 (proven)

    // Q fragments (B-operand): lane(g,c) holds Q[q=qlo+c][d=db*32+g*8+i]
    s16x8 qf[4];
    {
        const float* qrow = q + (((size_t)b * SQ_ + qr) * HQ_ + h) * D_;
        #pragma unroll
        for (int db = 0; db < 4; ++db){
            float4 x = *(const float4*)(qrow + db * 32 + g * 8);
            float4 y = *(const float4*)(qrow + db * 32 + g * 8 + 4);
            s16x8 f;
            f[0]=bf16b(x.x); f[1]=bf16b(x.y); f[2]=bf16b(x.z); f[3]=bf16b(x.w);
            f[4]=bf16b(y.x); f[5]=bf16b(y.y); f[6]=bf16b(y.z); f[7]=bf16b(y.w);
            qf[db] = f;
        }
    }

    const float SCALE = 0.08838834764831845f;
    const float L2E   = 1.4426950408889634f;
    const float C1 = 2.0f * SCALE / 30.0f * L2E;
    const float C2 = -60.0f * L2E;
    const float C3 =  30.0f * L2E;

    // staging assignments
    int skrow = tid >> 3, sdg = tid & 7;          // K: row, 16-float group
    int svp = tid & 31, svd = tid >> 5;           // V: kv-pair, 8-d group (0..15)
    const float* kbase = k + ((size_t)b * SK_ * HKV_ + hkv) * D_;
    const float* vbase = v + ((size_t)b * SK_ * HKV_ + hkv) * D_;

    float4 st[4];
    auto issueK = [&](int t){
        const float* p = kbase + (size_t)(t + skrow) * (HKV_ * D_) + sdg * 16;
        st[0] = *(const float4*)p;       st[1] = *(const float4*)(p + 4);
        st[2] = *(const float4*)(p + 8); st[3] = *(const float4*)(p + 12);
    };
    auto writeK = [&](){
        const float* f = (const float*)st;
        #pragma unroll
        for (int s = 0; s < 2; ++s){
            s16x8 o8;
            #pragma unroll
            for (int i = 0; i < 8; ++i) o8[i] = bf16b(f[s * 8 + i]);
            int byte = skrow * 256 + (((sdg * 32 + s * 16)) ^ ((skrow & 7) << 4));
            *(s16x8*)((char*)KV + byte) = o8;
        }
    };
    auto issueV = [&](int t){
        const float* p0 = vbase + (size_t)(t + 2 * svp) * (HKV_ * D_) + svd * 8;
        const float* p1 = p0 + HKV_ * D_;
        st[0] = *(const float4*)p0; st[1] = *(const float4*)(p0 + 4);
        st[2] = *(const float4*)p1; st[3] = *(const float4*)(p1 + 4);
    };
    auto writeV = [&](){
        const float* f = (const float*)st;
        #pragma unroll
        for (int i = 0; i < 8; ++i){
            int d = svd * 8 + i;
            unsigned wd = pk2(f[i], f[8 + i]);   // (kv=2svp, 2svp+1) at depth d
            int byte = (d * 128 + svp * 4) ^ ((d & 7) << 4);
            *(unsigned*)((char*)KV + byte) = wd;
        }
    };

    // ---------------- pass A: K staging + QK^T -> u (registers) + row sums ----------------
    float ls = 0.f;
    unsigned wv[MAXT][8];
    issueK(t0);
    #pragma unroll
    for (int ti = 0; ti < MAXT; ++ti){
        if (ti < nt){
            int t = t0 + ti * 64;
            __syncthreads();                 // prior tile's readers done
            writeK();
            if (ti + 1 < nt) issueK(t0 + (ti + 1) * 64);
            __syncthreads();                 // K tile ready
            #pragma unroll
            for (int hh = 0; hh < 4; ++hh){
                int row = hh * 16 + c;
                f32x4 acc = {0.f, 0.f, 0.f, 0.f};
                #pragma unroll
                for (int db = 0; db < 4; ++db){
                    s16x8 kf = *(const s16x8*)((char*)KV + row * 256 + ((db * 64 + g * 16) ^ ((c & 7) << 4)));
                    acc = __builtin_amdgcn_mfma_f32_16x16x32_bf16(kf, qf[db], acc, 0, 0, 0);
                }
                int kvb = t + hh * 16 + 4 * g;
                float u[4];
                #pragma unroll
                for (int j = 0; j < 4; ++j){
                    float e = fexp2(acc[j] * C1);
                    float r = __builtin_amdgcn_rcpf(e + 1.0f);
                    float uu = fexp2(fmaf(r, C2, C3));
                    int kv = kvb + j;
                    bool ok = (kv <= qr) && (kv >= qr - W_);
                    u[j] = ok ? uu : 0.f;
                    ls += u[j];
                }
                wv[ti][hh * 2 + 0] = pk2(u[0], u[1]);
                wv[ti][hh * 2 + 1] = pk2(u[2], u[3]);
            }
        }
    }

    ls += __shfl_xor(ls, 16);
    ls += __shfl_xor(ls, 32);
    float rl = 1.02f / ls;

    // ---------------- pass B: V staging + bounce + p' + PV ----------------
    f32x4 o[8];
    #pragma unroll
    for (int dt = 0; dt < 8; ++dt) o[dt] = (f32x4){0.f, 0.f, 0.f, 0.f};

    char* myPb = (char*)(Pb + w * 1024);     // 2 KB slice (1024 shorts)

    issueV(t0);
    #pragma unroll
    for (int ti = 0; ti < MAXT; ++ti){
        if (ti < nt){
            __syncthreads();                 // prior tile's readers done (also pass-A exit)
            writeV();
            if (ti + 1 < nt) issueV(t0 + (ti + 1) * 64);
            __syncthreads();                 // V tile ready
            // bounce wv[ti]: D-layout [kv=hh*16+4g+2pr(+1)][q=c] -> row q=c
            #pragma unroll
            for (int e = 0; e < 8; ++e){
                int hh = e >> 1, pr = e & 1;
                int byte = c * 128 + ((hh * 32 + g * 8 + pr * 4) ^ ((c & 7) << 4));
                *(unsigned*)(myPb + byte) = wv[ti][e];
            }
            asm volatile("s_waitcnt lgkmcnt(0)" ::: "memory");
            #pragma unroll
            for (int ks = 0; ks < 2; ++ks){
                // PV A-frag: lane(g,c) = P[q=c][kv = ks*32 + g*8 .. +7]
                s16x8 pa = *(const s16x8*)(myPb + c * 128 + ((ks * 64 + g * 16) ^ ((c & 7) << 4)));
                s16x8 pf;
                #pragma unroll
                for (int i = 0; i < 8; ++i){
                    float p = fmaf(b2f(pa[i]), rl, -0.01f);
                    p = fminf(fmaxf(p, 0.f), 1.f);
                    pf[i] = bf16b(p);
                }
                #pragma unroll
                for (int dt = 0; dt < 8; ++dt){
                    int d = dt * 16 + c;
                    s16x8 vf = *(const s16x8*)((char*)KV + d * 128 + ((ks * 64 + g * 16) ^ ((d & 7) << 4)));
                    o[dt] = __builtin_amdgcn_mfma_f32_16x16x32_bf16(pf, vf, o[dt], 0, 0, 0);
                }
            }
        }
    }

    // epilogue: o[dt][j] = O[q = qlo + 4g + j][d = dt*16 + c]
    float* ob = out + (((size_t)b * SQ_ + qlo) * HQ_ + h) * D_;
    #pragma unroll
    for (int dt = 0; dt < 8; ++dt){
        #pragma unroll
        for (int j = 0; j < 4; ++j){
            ob[(size_t)(4 * g + j) * (HQ_ * D_) + dt * 16 + c] = o[dt][j];
        }
    }
}

extern "C" void kernel_launch(void* const* d_in, const int* in_sizes, int n_in,
                              void* d_out, int out_size, void* d_ws, size_t ws_size,
                              hipStream_t stream){
    const float* q = (const float*)d_in[0];
    const float* k = (const float*)d_in[1];
    const float* v = (const float*)d_in[2];
    float* out = (float*)d_out;

    attn_kernel<<<B_ * HKV_ * (SQ_ / 32), 512, 0, stream>>>(q, k, v, out);
}

// Round 6
// 208.514 us; speedup vs baseline: 2.3637x; 1.0864x over previous
//
#include <hip/hip_runtime.h>
#include <hip/hip_bf16.h>

#define B_    2
#define SQ_   2048
#define SK_   2048
#define HQ_   32
#define HKV_  8
#define D_    128
#define W_    512
#define KVT   64
#define MAXT  9

typedef short s16x8 __attribute__((ext_vector_type(8)));
typedef float f32x4 __attribute__((ext_vector_type(4)));

static __device__ __forceinline__ short bf16b(float x){
    __hip_bfloat16 h = __float2bfloat16(x);
    return *reinterpret_cast<short*>(&h);
}
static __device__ __forceinline__ float b2f(short u){
    return __uint_as_float(((unsigned)(unsigned short)u) << 16);
}
static __device__ __forceinline__ float fexp2(float x){ return __builtin_amdgcn_exp2f(x); }
static __device__ __forceinline__ unsigned pk2(float a, float b){
    return ((unsigned)(unsigned short)bf16b(a)) | (((unsigned)(unsigned short)bf16b(b)) << 16);
}

// ---- prep: cast fp32 -> bf16, same layout; used for K and V ----
__global__ void cast_bf16(const float* __restrict__ src, short* __restrict__ dst){
    int idx = blockIdx.x * 256 + threadIdx.x;
    const float4* p = reinterpret_cast<const float4*>(src) + (size_t)idx * 2;
    float4 a = p[0], b = p[1];
    s16x8 o;
    o[0]=bf16b(a.x); o[1]=bf16b(a.y); o[2]=bf16b(a.z); o[3]=bf16b(a.w);
    o[4]=bf16b(b.x); o[5]=bf16b(b.y); o[6]=bf16b(b.z); o[7]=bf16b(b.w);
    reinterpret_cast<s16x8*>(dst)[idx] = o;
}

// Block = 512 thr = 8 waves = 4 heads x 2 kv-halves, 16 q rows.
// Double-buffered block-wide tile staging (bf16 in, 1 barrier/tile).
// Pass A: swapped QK^T (mfma(K,Q) -> S^T, lane q-row = c), u = exp(CAP*tanh(.)),
//   kept in registers wv[9][4] (each wave: its 32-kv half only).
// l: 2 shfl_xor + cross-pair LDS. Pass B: V^T staged, wv -> 1KB/wave bounce ->
//   PV A-frag, p' = clamp(1.02*u/l - 0.01, 0, 1), 8 MFMA/tile.
// O: partial across kv-halves, combined through LDS at the end.
__global__ __launch_bounds__(512, 4)
void attn_kernel(const float* __restrict__ q, const short* __restrict__ kb,
                 const short* __restrict__ vb, float* __restrict__ out){
    __shared__ short KVb[2][KVT * D_];   // 2 x 16 KB
    __shared__ short Pbb[8 * 16 * 32];   // 8 KB bounce (1 KB per wave)
    __shared__ float Ls[8][16];

    int bid = blockIdx.x;
    int swz = (bid & 7) * 256 + (bid >> 3);   // XCD swizzle, bijective (2048 = 8*256)
    int qt  = swz & 127;
    int hkv = (swz >> 7) & 7;
    int b   = swz >> 10;
    int qb  = qt * 16;

    int tid = threadIdx.x;
    int w = tid >> 6, lane = tid & 63;
    int hl = w & 3, s = w >> 2;               // head-in-group, kv-half
    int h = hkv * 4 + hl;
    int g = lane >> 4, c = lane & 15;
    int qr = qb + c;

    int t0 = qb >= 512 ? ((qb - 512) & ~63) : 0;
    int nt = (qb + 16 - t0 + 63) >> 6;        // <= 9

    // Q B-frag: lane(g,c) holds Q[q=qb+c][d=db*32+g*8+i]
    s16x8 qf[4];
    {
        const float* qrow = q + (((size_t)b * SQ_ + qr) * HQ_ + h) * D_;
        #pragma unroll
        for (int db = 0; db < 4; ++db){
            float4 x = *(const float4*)(qrow + db * 32 + g * 8);
            float4 y = *(const float4*)(qrow + db * 32 + g * 8 + 4);
            s16x8 f;
            f[0]=bf16b(x.x); f[1]=bf16b(x.y); f[2]=bf16b(x.z); f[3]=bf16b(x.w);
            f[4]=bf16b(y.x); f[5]=bf16b(y.y); f[6]=bf16b(y.z); f[7]=bf16b(y.w);
            qf[db] = f;
        }
    }

    const float SCALE = 0.08838834764831845f;
    const float L2E   = 1.4426950408889634f;
    const float C1 = 2.0f * SCALE / 30.0f * L2E;
    const float C2 = -60.0f * L2E;
    const float C3 =  30.0f * L2E;

    // staging thread assignments
    int skr = tid >> 3, sdg = tid & 7;        // K: row, 32B group
    int svp = tid & 31, svd = tid >> 5;       // V: kv-pair, 8-d group (0..15)
    const short* kbase = kb + ((size_t)b * SK_ * HKV_ + hkv) * D_;
    const short* vbase = vb + ((size_t)b * SK_ * HKV_ + hkv) * D_;

    s16x8 st16[2];
    auto issueK = [&](int t){
        const short* p = kbase + (size_t)(t + skr) * (HKV_ * D_) + sdg * 16;
        st16[0] = *(const s16x8*)p;
        st16[1] = *(const s16x8*)(p + 8);
    };
    auto writeK = [&](short* buf){
        #pragma unroll
        for (int s2 = 0; s2 < 2; ++s2){
            int byte = skr * 256 + (((2 * sdg + s2) ^ (skr & 15)) << 4);
            *(s16x8*)((char*)buf + byte) = st16[s2];
        }
    };
    auto issueV = [&](int t){
        const short* p0 = vbase + (size_t)(t + 2 * svp) * (HKV_ * D_) + svd * 8;
        st16[0] = *(const s16x8*)p0;
        st16[1] = *(const s16x8*)(p0 + HKV_ * D_);
    };
    auto writeV = [&](short* buf){
        #pragma unroll
        for (int i = 0; i < 8; ++i){
            int d = svd * 8 + i;
            unsigned wd = ((unsigned)(unsigned short)st16[0][i]) |
                          (((unsigned)(unsigned short)st16[1][i]) << 16);
            int byte = d * 128 + ((svp ^ (i << 2)) << 2);
            *(unsigned*)((char*)buf + byte) = wd;
        }
    };

    // ---------------- pass A: QK^T -> u (registers), row sums ----------------
    float ls = 0.f;
    unsigned wv[MAXT][4];
    issueK(t0);
    writeK(KVb[0]);
    __syncthreads();
    #pragma unroll
    for (int ti = 0; ti < MAXT; ++ti){
        if (ti < nt){
            int t = t0 + ti * 64;
            const short* buf = KVb[ti & 1];
            if (ti + 1 < nt) issueK(t0 + (ti + 1) * 64);
            #pragma unroll
            for (int kvb = 0; kvb < 2; ++kvb){
                int row = s * 32 + kvb * 16 + c;
                f32x4 acc = {0.f, 0.f, 0.f, 0.f};
                __builtin_amdgcn_s_setprio(1);
                #pragma unroll
                for (int db = 0; db < 4; ++db){
                    s16x8 kf = *(const s16x8*)((char*)buf + row * 256 + (((db * 4 + g) ^ c) << 4));
                    acc = __builtin_amdgcn_mfma_f32_16x16x32_bf16(kf, qf[db], acc, 0, 0, 0);
                }
                __builtin_amdgcn_s_setprio(0);
                int kvb0 = t + s * 32 + kvb * 16 + 4 * g;
                float u[4];
                #pragma unroll
                for (int j = 0; j < 4; ++j){
                    float e = fexp2(acc[j] * C1);
                    float r = __builtin_amdgcn_rcpf(e + 1.0f);
                    float uu = fexp2(fmaf(r, C2, C3));
                    int kv = kvb0 + j;
                    bool ok = (kv <= qr) && (kv >= qr - W_);
                    u[j] = ok ? uu : 0.f;
                    ls += u[j];
                }
                wv[ti][kvb * 2 + 0] = pk2(u[0], u[1]);
                wv[ti][kvb * 2 + 1] = pk2(u[2], u[3]);
            }
            if (ti + 1 < nt){ writeK(KVb[(ti + 1) & 1]); __syncthreads(); }
        }
    }

    // row-sum over this wave's half, then combine across the kv-pair
    ls += __shfl_xor(ls, 16);
    ls += __shfl_xor(ls, 32);
    if (lane < 16) Ls[w][lane] = ls;
    issueV(t0);
    __syncthreads();
    float rl = 1.02f / (Ls[hl][c] + Ls[hl + 4][c]);

    // ---------------- pass B: V^T staging + bounce + p' + PV ----------------
    f32x4 o[8];
    #pragma unroll
    for (int dt = 0; dt < 8; ++dt) o[dt] = (f32x4){0.f, 0.f, 0.f, 0.f};

    char* myPb = (char*)Pbb + w * 1024;       // 16 rows x 64 B
    int q2 = (c >> 1) & 3;

    writeV(KVb[0]);
    __syncthreads();
    #pragma unroll
    for (int ti = 0; ti < MAXT; ++ti){
        if (ti < nt){
            const short* buf = KVb[ti & 1];
            if (ti + 1 < nt) issueV(t0 + (ti + 1) * 64);
            // bounce wv[ti] -> PV A-frag layout (row q=c, 32 kv of this half)
            #pragma unroll
            for (int e = 0; e < 4; ++e){
                int kvb = e >> 1, pr = e & 1;
                int byte = c * 64 + (((kvb * 2 + (g >> 1)) ^ q2) << 4) + (g & 1) * 8 + pr * 4;
                *(unsigned*)(myPb + byte) = wv[ti][e];
            }
            asm volatile("s_waitcnt lgkmcnt(0)" ::: "memory");
            __builtin_amdgcn_sched_barrier(0);
            s16x8 pa = *(const s16x8*)(myPb + c * 64 + ((g ^ q2) << 4));
            s16x8 pf;
            #pragma unroll
            for (int i = 0; i < 8; ++i){
                float p = fmaf(b2f(pa[i]), rl, -0.01f);
                p = fminf(fmaxf(p, 0.f), 1.f);
                pf[i] = bf16b(p);
            }
            __builtin_amdgcn_s_setprio(1);
            #pragma unroll
            for (int dt = 0; dt < 8; ++dt){
                int d = dt * 16 + c;
                s16x8 vf = *(const s16x8*)((char*)buf + d * 128 + (((s * 4 + g) ^ (c & 7)) << 4));
                o[dt] = __builtin_amdgcn_mfma_f32_16x16x32_bf16(pf, vf, o[dt], 0, 0, 0);
            }
            __builtin_amdgcn_s_setprio(0);
            if (ti + 1 < nt){ writeV(KVb[(ti + 1) & 1]); __syncthreads(); }
        }
    }

    // ---------------- combine kv-halves, store ----------------
    __syncthreads();                           // all PV reads done before reuse of KVb
    float* Ob = (float*)KVb;                   // 32 KB = 4 heads x 16q x 128d fp32
    if (s == 1){
        #pragma unroll
        for (int dt = 0; dt < 8; ++dt)
            #pragma unroll
            for (int j = 0; j < 4; ++j)
                Ob[hl * 2048 + (dt * 4 + j) * 64 + lane] = o[dt][j];
    }
    __syncthreads();
    if (s == 0){
        float* ob = out + (((size_t)b * SQ_ + qb) * HQ_ + h) * D_;
        #pragma unroll
        for (int dt = 0; dt < 8; ++dt)
            #pragma unroll
            for (int j = 0; j < 4; ++j){
                float r2 = o[dt][j] + Ob[hl * 2048 + (dt * 4 + j) * 64 + lane];
                ob[(size_t)(4 * g + j) * (HQ_ * D_) + dt * 16 + c] = r2;
            }
    }
}

extern "C" void kernel_launch(void* const* d_in, const int* in_sizes, int n_in,
                              void* d_out, int out_size, void* d_ws, size_t ws_size,
                              hipStream_t stream){
    const float* q = (const float*)d_in[0];
    const float* k = (const float*)d_in[1];
    const float* v = (const float*)d_in[2];
    float* out = (float*)d_out;

    short* kbp = (short*)d_ws;                 // 8 MiB
    short* vbp = (short*)d_ws + 4194304;       // 8 MiB

    cast_bf16<<<2048, 256, 0, stream>>>(k, kbp);
    cast_bf16<<<2048, 256, 0, stream>>>(v, vbp);
    attn_kernel<<<B_ * HKV_ * (SQ_ / 16), 512, 0, stream>>>(q, kbp, vbp, out);
}